// Round 4
// baseline (287.198 us; speedup 1.0000x reference)
//
#include <hip/hip_runtime.h>
#include <hip/hip_bf16.h>

#define MDIM 49
#define INF 128
#define OUTF 128
#define BDIM 16384
#define ROWS 16                         // b-rows per wave-tile
#define T_PER_BLK 16                    // tiles per block
#define BLOCKS_PER_M (BDIM / (ROWS * T_PER_BLK))   // 64

typedef __attribute__((ext_vector_type(8))) short bf16x8;
typedef __attribute__((ext_vector_type(4))) float f32x4;

static __device__ __forceinline__ short f2bf(float f) {
  __hip_bfloat16 h = __float2bfloat16(f);
  union { __hip_bfloat16 h; unsigned short u; } c;
  c.h = h;
  return (short)c.u;
}

static __device__ __forceinline__ bf16x8 cvt8(f32x4 a, f32x4 b) {
  bf16x8 r;
  r[0] = f2bf(a[0]); r[1] = f2bf(a[1]); r[2] = f2bf(a[2]); r[3] = f2bf(a[3]);
  r[4] = f2bf(b[0]); r[5] = f2bf(b[1]); r[6] = f2bf(b[2]); r[7] = f2bf(b[3]);
  return r;
}

// Wave-independent, LDS-free, barrier-free design.
// Block = 4 waves sharing the same 16-row input tiles (dedup'd in L1);
// wave wv owns output cols [wv*32, wv*32+32) with weights in registers.
// Each wave: reg-prefetch next tile -> cvt -> 8 MFMA -> f32x4 stores. No syncs.
__global__ __launch_bounds__(256) void so3_linear_kernel(
    const float* __restrict__ in, const float* __restrict__ wt,
    const float* __restrict__ bias, float* __restrict__ out) {
  const int m    = blockIdx.x;   // 0..48
  const int blk  = blockIdx.y;   // 0..BLOCKS_PER_M-1
  const int tid  = threadIdx.x;
  const int lane = tid & 63;
  const int wv   = tid >> 6;     // wave 0..3

  // expand_index: l = floor(sqrt(m))
  int l = 0;
  while ((l + 1) * (l + 1) <= m) ++l;

  const int colbase = wv * 32;
  const int r16     = lane & 15;        // row-within-16 / frag index
  const int koff    = (lane >> 4) * 8;  // k sub-chunk

  // ---- weight fragments (A operand): W[o][k], o = colbase+ct*16+r16
  const float* wl = wt + (size_t)l * OUTF * INF;
  bf16x8 wfrag[2][4];  // [o-tile][k-step]
#pragma unroll
  for (int ct = 0; ct < 2; ++ct) {
    const float* wp = wl + (size_t)(colbase + ct * 16 + r16) * INF + koff;
#pragma unroll
    for (int ks = 0; ks < 4; ++ks) {
      f32x4 w0 = *(const f32x4*)(wp + ks * 32);
      f32x4 w1 = *(const f32x4*)(wp + ks * 32 + 4);
      wfrag[ct][ks] = cvt8(w0, w1);
    }
  }

  // bias per lane: lane stores o = colbase + ct*16 + (lane>>4)*4 + j
  f32x4 biasadd[2];
#pragma unroll
  for (int ct = 0; ct < 2; ++ct) {
    biasadd[ct] = (m == 0)
        ? *(const f32x4*)(bias + colbase + ct * 16 + (lane >> 4) * 4)
        : (f32x4){0.f, 0.f, 0.f, 0.f};
  }

  const size_t rowstride = (size_t)MDIM * INF;  // 6272 floats per b
  const int b0 = blk * (T_PER_BLK * ROWS);

  // X fragment source: lane reads in[b0 + t*16 + r16][m*128 + ks*32 + koff .. +7]
  const float* ip0 = in + ((size_t)(b0 + r16) * rowstride) + (size_t)m * INF + koff;

  // prefetch tile 0
  f32x4 pf[8];
#pragma unroll
  for (int ks = 0; ks < 4; ++ks) {
    pf[2 * ks]     = *(const f32x4*)(ip0 + ks * 32);
    pf[2 * ks + 1] = *(const f32x4*)(ip0 + ks * 32 + 4);
  }

  for (int t = 0; t < T_PER_BLK; ++t) {
    // cvt current tile regs -> bf16 X fragments
    bf16x8 xfrag[4];
#pragma unroll
    for (int ks = 0; ks < 4; ++ks) xfrag[ks] = cvt8(pf[2 * ks], pf[2 * ks + 1]);

    // issue next tile's loads (land under this tile's MFMA + stores)
    if (t + 1 < T_PER_BLK) {
      const float* ip = ip0 + (size_t)(t + 1) * ROWS * rowstride;
#pragma unroll
      for (int ks = 0; ks < 4; ++ks) {
        pf[2 * ks]     = *(const f32x4*)(ip + ks * 32);
        pf[2 * ks + 1] = *(const f32x4*)(ip + ks * 32 + 4);
      }
    }

    // D[o][b] = W x X : 2 o-tiles x 4 k-steps
    f32x4 acc[2];
    acc[0] = (f32x4){0.f, 0.f, 0.f, 0.f};
    acc[1] = (f32x4){0.f, 0.f, 0.f, 0.f};
#pragma unroll
    for (int ks = 0; ks < 4; ++ks) {
      acc[0] = __builtin_amdgcn_mfma_f32_16x16x32_bf16(wfrag[0][ks], xfrag[ks], acc[0], 0, 0, 0);
      acc[1] = __builtin_amdgcn_mfma_f32_16x16x32_bf16(wfrag[1][ks], xfrag[ks], acc[1], 0, 0, 0);
    }

    // D layout: col(lane&15)=b, row((lane>>4)*4+j)=o -> one f32x4 store per o-tile
    const int b = b0 + t * ROWS + r16;
    float* op = out + (size_t)b * rowstride + (size_t)m * OUTF + colbase + (lane >> 4) * 4;
#pragma unroll
    for (int ct = 0; ct < 2; ++ct) {
      f32x4 v = acc[ct];
      v[0] += biasadd[ct][0]; v[1] += biasadd[ct][1];
      v[2] += biasadd[ct][2]; v[3] += biasadd[ct][3];
      *(f32x4*)(op + ct * 16) = v;
    }
  }
}

extern "C" void kernel_launch(void* const* d_in, const int* in_sizes, int n_in,
                              void* d_out, int out_size, void* d_ws, size_t ws_size,
                              hipStream_t stream) {
  const float* in   = (const float*)d_in[0];
  const float* wt   = (const float*)d_in[1];
  const float* bias = (const float*)d_in[2];
  float* out        = (float*)d_out;
  dim3 grid(MDIM, BLOCKS_PER_M);
  so3_linear_kernel<<<grid, dim3(256), 0, stream>>>(in, wt, bias, out);
}

// Round 5
// 164.922 us; speedup vs baseline: 1.7414x; 1.7414x over previous
//
#include <hip/hip_runtime.h>
#include <hip/hip_bf16.h>

#define MDIM 49
#define INF 128
#define OUTF 128
#define BDIM 16384
#define BT 64
#define TILES_PER_BLOCK 4
#define BLOCKS_PER_M (BDIM / (BT * TILES_PER_BLOCK))   // 64

typedef __attribute__((ext_vector_type(8))) short bf16x8;
typedef __attribute__((ext_vector_type(4))) float f32x4;

static __device__ __forceinline__ short f2bf(float f) {
  __hip_bfloat16 h = __float2bfloat16(f);
  union { __hip_bfloat16 h; unsigned short u; } c;
  c.h = h;
  return (short)c.u;
}

static __device__ __forceinline__ bf16x8 cvt8(f32x4 a, f32x4 b) {
  bf16x8 r;
  r[0] = f2bf(a[0]); r[1] = f2bf(a[1]); r[2] = f2bf(a[2]); r[3] = f2bf(a[3]);
  r[4] = f2bf(b[0]); r[5] = f2bf(b[1]); r[6] = f2bf(b[2]); r[7] = f2bf(b[3]);
  return r;
}

// LDS barrier that does NOT drain vmcnt: ds-op ordering only (lgkmcnt).
// Private global prefetch loads legally stay in flight across it; the
// compiler still inserts vmcnt waits before their results are used.
static __device__ __forceinline__ void lds_barrier() {
  asm volatile("s_waitcnt lgkmcnt(0)\n\ts_barrier" ::: "memory");
}

__global__ __launch_bounds__(256) void so3_linear_kernel(
    const float* __restrict__ in, const float* __restrict__ wt,
    const float* __restrict__ bias, float* __restrict__ out) {
  const int m    = blockIdx.x;   // 0..48
  const int blk  = blockIdx.y;   // 0..BLOCKS_PER_M-1
  const int tid  = threadIdx.x;
  const int lane = tid & 63;
  const int wv   = tid >> 6;     // wave 0..3

  // expand_index: l = floor(sqrt(m))
  int l = 0;
  while ((l + 1) * (l + 1) <= m) ++l;

  // input tile staged as bf16, padded to 136 shorts/row (272 B stride: 2-way alias = free)
  __shared__ short lds[BT][INF + 8];

  // ---- weight fragments (operand B): wave wv owns output cols [wv*32, wv*32+32)
  const int colbase = wv * 32;
  const int col0    = colbase + (lane & 15);
  const int krow    = (lane >> 4) * 8;
  const float* wl   = wt + (size_t)l * OUTF * INF;
  bf16x8 bfrag[2][4];  // [col-tile][k-step]
#pragma unroll
  for (int ct = 0; ct < 2; ++ct) {
    const float* wp = wl + (size_t)(col0 + ct * 16) * INF + krow;
#pragma unroll
    for (int ks = 0; ks < 4; ++ks) {
      f32x4 w0 = *(const f32x4*)(wp + ks * 32);
      f32x4 w1 = *(const f32x4*)(wp + ks * 32 + 4);
      bfrag[ct][ks] = cvt8(w0, w1);
    }
  }
  float biasv[2];
  biasv[0] = bias[col0];
  biasv[1] = bias[col0 + 16];

  // staging map: thread -> (row r0 + 16p, 8-float chunk c8)
  const int c8 = (tid & 15) * 8;
  const int r0 = tid >> 4;
  const int b0 = blk * (TILES_PER_BLOCK * BT);

  const size_t rowstride = (size_t)MDIM * INF;  // 6272 floats between consecutive b

  // prefetch tile 0 into registers
  f32x4 pf[8];
  {
    const float* ip = in + ((size_t)(b0 + r0) * MDIM + m) * INF + c8;
#pragma unroll
    for (int p = 0; p < 4; ++p) {
      pf[2 * p]     = *(const f32x4*)(ip + p * 16 * rowstride);
      pf[2 * p + 1] = *(const f32x4*)(ip + p * 16 * rowstride + 4);
    }
  }

  for (int tt = 0; tt < TILES_PER_BLOCK; ++tt) {
    // convert current tile regs -> bf16 LDS
#pragma unroll
    for (int p = 0; p < 4; ++p) {
      *(bf16x8*)&lds[r0 + 16 * p][c8] = cvt8(pf[2 * p], pf[2 * p + 1]);
    }

    // issue next tile's global loads; they now stay in flight across the
    // lgkmcnt-only barrier and land under MFMA + stores.
    if (tt + 1 < TILES_PER_BLOCK) {
      const float* ip =
          in + ((size_t)(b0 + (tt + 1) * BT + r0) * MDIM + m) * INF + c8;
#pragma unroll
      for (int p = 0; p < 4; ++p) {
        pf[2 * p]     = *(const f32x4*)(ip + p * 16 * rowstride);
        pf[2 * p + 1] = *(const f32x4*)(ip + p * 16 * rowstride + 4);
      }
    }

    lds_barrier();  // ds_writes visible; prefetch NOT drained

    // compute: wave covers all 64 rows x its 32 cols, K=128
    f32x4 acc[4][2];
#pragma unroll
    for (int rt = 0; rt < 4; ++rt)
#pragma unroll
      for (int ct = 0; ct < 2; ++ct)
        acc[rt][ct] = (f32x4){0.f, 0.f, 0.f, 0.f};

#pragma unroll
    for (int rt = 0; rt < 4; ++rt) {
      const int arow = rt * 16 + (lane & 15);
#pragma unroll
      for (int ks = 0; ks < 4; ++ks) {
        bf16x8 a = *(const bf16x8*)&lds[arow][ks * 32 + krow];
        acc[rt][0] = __builtin_amdgcn_mfma_f32_16x16x32_bf16(
            a, bfrag[0][ks], acc[rt][0], 0, 0, 0);
        acc[rt][1] = __builtin_amdgcn_mfma_f32_16x16x32_bf16(
            a, bfrag[1][ks], acc[rt][1], 0, 0, 0);
      }
    }

    // epilogue: C/D layout col=lane&15, row=(lane>>4)*4+j
    const int btile = b0 + tt * BT;
#pragma unroll
    for (int rt = 0; rt < 4; ++rt) {
      const int rbase = btile + rt * 16 + (lane >> 4) * 4;
#pragma unroll
      for (int ct = 0; ct < 2; ++ct) {
        const int col = colbase + ct * 16 + (lane & 15);
        const float badd = (m == 0) ? biasv[ct] : 0.0f;
#pragma unroll
        for (int j = 0; j < 4; ++j) {
          out[((size_t)(rbase + j) * MDIM + m) * OUTF + col] = acc[rt][ct][j] + badd;
        }
      }
    }

    lds_barrier();  // ds_reads done before next tile's ds_writes
  }
}

extern "C" void kernel_launch(void* const* d_in, const int* in_sizes, int n_in,
                              void* d_out, int out_size, void* d_ws, size_t ws_size,
                              hipStream_t stream) {
  const float* in   = (const float*)d_in[0];
  const float* wt   = (const float*)d_in[1];
  const float* bias = (const float*)d_in[2];
  float* out        = (float*)d_out;
  dim3 grid(MDIM, BLOCKS_PER_M);
  so3_linear_kernel<<<grid, dim3(256), 0, stream>>>(in, wt, bias, out);
}